// Round 14
// baseline (221.274 us; speedup 1.0000x reference)
//
#include <hip/hip_runtime.h>

// Problem constants
#define NB 2
#define DD 192
#define HH 192
#define WW 192
#define HWSZ (HH * WW)
#define C1F 0.0001f
#define C2F 0.0009f

// Tiling: 32(H) x 32(W) outputs per block-slice, 512 threads, stream D.
#define TH 32
#define TW 32
#define CHUNK 32
#define TSTEPS (CHUNK + 10)          // 42
#define NCH (DD / CHUNK)             // 6
#define NTH (HH / TH)                // 6
#define NTW (WW / TW)                // 6
#define NBLK (NB * NCH * NTH * NTW)  // 432
#define NTHR 512

#define SROWS (TH + 10)              // 42 staged/W-blurred rows
#define SCOLS 42                     // staged cols (w0-5 .. w0+36)
#define SP2 50                       // s2 row stride in float2 (100 words = 4 mod 32)
#define TQ 33                        // t4 row stride in quads (132 words = 4 mod 32)
#define NSTG (SROWS * SCOLS)         // 1764 stage tasks (4 rounds of 512)
#define NWT (SROWS * (TW / 4))       // 336 W-blur tasks

// Gaussian weights, WIN=11, sigma=1.5
#define KWLIST { 0.00102838f, 0.00759876f, 0.03600077f, 0.10936071f, 0.21300556f, \
                 0.26601172f, 0.21300556f, 0.10936071f, 0.03600077f, 0.00759876f, 0.00102838f }

// Packed f32 FMA: acc(2xf32) += a(2xf32) * k2(2xf32, broadcast pair in VGPRs).
// NOTE: VOP3P operands are 64-bit; a scalar source would need an SGPR PAIR,
// so we pass the broadcast weight as a VGPR pair instead (R12 compile fix).
__device__ __forceinline__ void pk_fma(float2& acc, float2 a, float2 k2) {
  asm("v_pk_fma_f32 %0, %1, %2, %0" : "+v"(acc) : "v"(a), "v"(k2));
}

// SSIM from 4 packed stats: mu1, mu2, A=blur((x+y)^2), Bm=blur((x-y)^2).
__device__ __forceinline__ float ssim_val(float mu1, float mu2, float A, float Bm) {
  const float mu1sq = mu1 * mu1, mu2sq = mu2 * mu2, mu12 = mu1 * mu2;
  const float num = (2.f * mu12 + C1F) * (0.5f * (A - Bm) - 2.f * mu12 + C2F);
  const float den = (mu1sq + mu2sq + C1F) * (0.5f * (A + Bm) - mu1sq - mu2sq + C2F);
  return num * __builtin_amdgcn_rcpf(den);
}

__global__ __launch_bounds__(NTHR) void ssim_fused(
    const float* __restrict__ x, const float* __restrict__ y,
    float* __restrict__ partials) {
  const float KW[11] = KWLIST;
  float2 KW2[11];
#pragma unroll
  for (int i = 0; i < 11; ++i) KW2[i] = make_float2(KW[i], KW[i]);

  int bid = blockIdx.x;
  const int tw = bid % NTW; bid /= NTW;
  const int th = bid % NTH; bid /= NTH;
  const int c  = bid % NCH; bid /= NCH;
  const int b  = bid;
  const int h0 = th * TH, w0 = tw * TW, c0 = c * CHUNK;

  __shared__ __align__(16) float2 s2[2][SROWS][SP2];  // staged {x,y}, dbuf
  __shared__ float4 t4[SROWS][TQ];                    // W-blurred 4 fields

  const int tid = threadIdx.x;
  const int cl  = tid & 31;            // own W col
  const int rg  = tid >> 5;            // 0..15 row-group
  const int r0  = 2 * rg;              // own output rows r0, r0+1
  // t4 store-rotation inverse: pixel cl lives at (cl&~3)|(((cl&3)+(cl>>2))&3)
  const int clp2 = (cl & ~3) | (((cl & 3) + (cl >> 2)) & 3);

  // ---- hoisted stage-task addressing: 1764 scalar tasks, 4 rounds ----
  int  sIdx[4], sOff[4];
  bool sOk[4];
#pragma unroll
  for (int k = 0; k < 4; ++k) {
    const int q = tid + NTHR * k;
    const bool act = (q < NSTG);
    const int row = q / SCOLS, col = q % SCOLS;
    const int gh = h0 - 5 + row, gw = w0 - 5 + col;
    sOk[k]  = act && (unsigned)gh < (unsigned)HH && (unsigned)gw < (unsigned)WW;
    sIdx[k] = row * SP2 + col;
    sOff[k] = gh * WW + gw;
  }
  // W-blur task addressing (336 tasks); rotated store positions
  const bool wAct = (tid < NWT);
  const int  wr = tid >> 3;            // 0..41
  const int  wq = tid & 7;             // 0..7 (4-output group)
  const int  tBase = wr * TQ + 4 * wq;
  const int  st0 = tBase + ((0 + wq) & 3);
  const int  st1 = tBase + ((1 + wq) & 3);
  const int  st2 = tBase + ((2 + wq) & 3);
  const int  st3 = tBase + ((3 + wq) & 3);

  // zero-init both s2 buffers (OOB cols + pad cols stay zero all kernel)
  {
    const float2 z = make_float2(0.f, 0.f);
    float2* sb = &s2[0][0][0];
    for (int q = tid; q < 2 * SROWS * SP2; q += NTHR) sb[q] = z;
  }

  const float* xb = x + (size_t)b * DD * HWSZ;
  const float* yb = y + (size_t)b * DD * HWSZ;

  float px[4], py[4];
#pragma unroll
  for (int k = 0; k < 4; ++k) { px[k] = 0.f; py[k] = 0.f; }

  auto do_prefetch = [&](int g) {
    const float* xs = xb + (size_t)g * HWSZ;
    const float* ys = yb + (size_t)g * HWSZ;
#pragma unroll
    for (int k = 0; k < 4; ++k)
      if (sOk[k]) { px[k] = xs[sOff[k]]; py[k] = ys[sOff[k]]; }
  };
  auto do_stage = [&](float2* s2buf) {
#pragma unroll
    for (int k = 0; k < 4; ++k)
      if (sOk[k]) s2buf[sIdx[k]] = make_float2(px[k], py[k]);
  };
  auto do_wblur = [&](const float2* s2buf) {
    if (wAct) {
      const float4* srow4 = (const float4*)(s2buf + wr * SP2);
      float2 a0p = make_float2(0.f, 0.f), a0q = a0p, a1p = a0p, a1q = a0p,
             a2p = a0p, a2q = a0p, a3p = a0p, a3q = a0p;
#pragma unroll
      for (int u2 = 0; u2 < 7; ++u2) {
        const float4 v2 = srow4[2 * wq + u2];   // pixels 4wq+2u2, +1
#pragma unroll
        for (int h = 0; h < 2; ++h) {
          const int    u  = 2 * u2 + h;
          const float  xx = h ? v2.z : v2.x;
          const float  yy = h ? v2.w : v2.y;
          const float2 xy = make_float2(xx, yy);
          const float  sm = xx + yy, df = xx - yy;
          const float2 sqdq = make_float2(sm * sm, df * df);
          if (u <= 10)           { pk_fma(a0p, xy, KW2[u]);     pk_fma(a0q, sqdq, KW2[u]); }
          if (u >= 1 && u <= 11) { pk_fma(a1p, xy, KW2[u - 1]); pk_fma(a1q, sqdq, KW2[u - 1]); }
          if (u >= 2 && u <= 12) { pk_fma(a2p, xy, KW2[u - 2]); pk_fma(a2q, sqdq, KW2[u - 2]); }
          if (u >= 3)            { pk_fma(a3p, xy, KW2[u - 3]); pk_fma(a3q, sqdq, KW2[u - 3]); }
        }
      }
      float4* tb = &t4[0][0];
      tb[st0] = make_float4(a0p.x, a0p.y, a0q.x, a0q.y);
      tb[st1] = make_float4(a1p.x, a1p.y, a1q.x, a1q.y);
      tb[st2] = make_float4(a2p.x, a2p.y, a2q.x, a2q.y);
      tb[st3] = make_float4(a3p.x, a3p.y, a3q.x, a3q.y);
    }
  };

  // Ring accumulators as float2 pairs: p0a={mu1,mu2}, p0b={A,Bm} (row r0),
  // p1a/p1b (row r0+1). All indices compile-time.
  float2 p0a[11], p0b[11], p1a[11], p1b[11];
#pragma unroll
  for (int i = 0; i < 11; ++i) {
    p0a[i] = make_float2(0.f, 0.f); p0b[i] = p0a[i];
    p1a[i] = p0a[i]; p1b[i] = p0a[i];
  }

  float lsum = 0.f;

  // ---- prologue: stage slice c0-5 into s2[0], prefetch c0-4 ----
  __syncthreads();                       // init -> stage
  if (c0 - 5 >= 0) { do_prefetch(c0 - 5); do_stage(&s2[0][0][0]); }
  if (c0 - 4 >= 0) do_prefetch(c0 - 4);
  __syncthreads();

  int p = 0;   // t mod 11 (wave-uniform)
  for (int t = 0; t < TSTEPS; ++t) {
    const int cur = t & 1, nxt = cur ^ 1;
    const int d = c0 - 5 + t;
    const bool dv = (d >= 0) && (d < DD);   // block-uniform

    // ---- Phase A: W-blur(d) from s2[cur]; stage(d+1)->s2[nxt]; prefetch(d+2)
    if (dv) do_wblur(&s2[cur][0][0]);
    if ((t + 1) < TSTEPS && (d + 1) >= 0 && (d + 1) < DD) do_stage(&s2[nxt][0][0]);
    if ((t + 2) < TSTEPS && (d + 2) >= 0 && (d + 2) < DD) do_prefetch(d + 2);
    __syncthreads();

    // ---- Phase B: H-blur(d) + D-ring ----
    float2 B0a = make_float2(0.f, 0.f), B0b = B0a, B1a = B0a, B1b = B0a;
    if (dv) {
      const float4* tb = &t4[0][0];
#pragma unroll
      for (int u = 0; u < 12; ++u) {
        const float4 v = tb[(r0 + u) * TQ + clp2];
        const float2 vxy = make_float2(v.x, v.y);
        const float2 vzw = make_float2(v.z, v.w);
        if (u <= 10) { pk_fma(B0a, vxy, KW2[u]);     pk_fma(B0b, vzw, KW2[u]); }
        if (u >= 1)  { pk_fma(B1a, vxy, KW2[u - 1]); pk_fma(B1b, vzw, KW2[u - 1]); }
      }
    }

#define RING_CASE(P)                                                        \
    case P: {                                                               \
      if (dv) {                                                             \
        _Pragma("unroll")                                                   \
        for (int kk = 0; kk < 11; ++kk) {                                   \
          const int sl = (P + 1 + kk) % 11;                                 \
          pk_fma(p0a[sl], B0a, KW2[kk]); pk_fma(p0b[sl], B0b, KW2[kk]);     \
          pk_fma(p1a[sl], B1a, KW2[kk]); pk_fma(p1b[sl], B1b, KW2[kk]);     \
        }                                                                   \
      }                                                                     \
      const int sc = (P + 1) % 11;                                          \
      if (t >= 10) {                                                        \
        lsum += ssim_val(p0a[sc].x, p0a[sc].y, p0b[sc].x, p0b[sc].y);       \
        lsum += ssim_val(p1a[sc].x, p1a[sc].y, p1b[sc].x, p1b[sc].y);       \
      }                                                                     \
      p0a[sc] = make_float2(0.f, 0.f); p0b[sc] = make_float2(0.f, 0.f);     \
      p1a[sc] = make_float2(0.f, 0.f); p1b[sc] = make_float2(0.f, 0.f);     \
    } break;

    switch (p) {
      RING_CASE(0) RING_CASE(1) RING_CASE(2) RING_CASE(3) RING_CASE(4)
      RING_CASE(5) RING_CASE(6) RING_CASE(7) RING_CASE(8) RING_CASE(9)
      RING_CASE(10)
    }
#undef RING_CASE
    p = (p + 1 == 11) ? 0 : p + 1;

    __syncthreads();   // protects t4 overwrite + s2[nxt] read next step
  }

  // ---- block reduction: 8 waves ----
  for (int off = 32; off > 0; off >>= 1) lsum += __shfl_down(lsum, off, 64);
  __shared__ float wsum[8];
  if ((tid & 63) == 0) wsum[tid >> 6] = lsum;
  __syncthreads();
  if (tid == 0) {
    float s = 0.f;
#pragma unroll
    for (int i = 0; i < 8; ++i) s += wsum[i];
    partials[blockIdx.x] = s;
  }
}

// ---------------------------------------------------------------------------
// Final reduction: NBLK partials -> mean (deterministic, double).
// ---------------------------------------------------------------------------
__global__ __launch_bounds__(256) void ssim_reduce(
    const float* __restrict__ partials, float* __restrict__ out) {
  __shared__ double sd[256];
  double a = 0.0;
  for (int i = threadIdx.x; i < NBLK; i += 256) a += (double)partials[i];
  sd[threadIdx.x] = a;
  __syncthreads();
  for (int s = 128; s > 0; s >>= 1) {
    if ((int)threadIdx.x < s) sd[threadIdx.x] += sd[threadIdx.x + s];
    __syncthreads();
  }
  if (threadIdx.x == 0) {
    out[0] = (float)(sd[0] / (double)((size_t)NB * DD * HH * WW));
  }
}

extern "C" void kernel_launch(void* const* d_in, const int* in_sizes, int n_in,
                              void* d_out, int out_size, void* d_ws, size_t ws_size,
                              hipStream_t stream) {
  const float* img1 = (const float*)d_in[0];
  const float* img2 = (const float*)d_in[1];
  float* out = (float*)d_out;
  float* partials = (float*)d_ws;   // NBLK floats

  ssim_fused<<<NBLK, NTHR, 0, stream>>>(img1, img2, partials);
  ssim_reduce<<<1, 256, 0, stream>>>(partials, out);
}